// Round 9
// baseline (109.658 us; speedup 1.0000x reference)
//
#include <hip/hip_runtime.h>

#define BATCH  65536
#define NIN    9
#define NHID   100
#define TSTEPS 25
#define CHUNK  5

typedef float v2f __attribute__((ext_vector_type(2)));

// Wave-uniform neuron mapping: block = 64 batch elements (lane = batch elem),
// wave wq in the block owns neuron rows [25wq, 25wq+25) -> weight reads are
// wave-uniform => scalar (SGPR) loads, zero VALU issue for weights/addressing.
// f64 m-chain per neuron-step (tracks the f64 numpy arbiter; ~16 issue-cyc is
// the structural floor), packed f32 fc2 acc in arch VGPRs (~85-reg state).
// Cross-wave reduce via LDS in double-buffered 5-t chunks with explicit
// (q0+q1)+(q2+q3) bracketing == the old shuffle butterfly -> bit-identical
// output (absmax 0.1015625 expected, as rounds 2/4/5/7/8).
__global__ __launch_bounds__(256) void snn_kernel(
    const float* __restrict__ x,  const float* __restrict__ W1,
    const float* __restrict__ b1, const float* __restrict__ W2,
    const float* __restrict__ b2, float* __restrict__ out)
{
    __shared__ float sx[64 * NIN];              // 2.25 KB staged x rows
    __shared__ v2f   sacc[2][4][CHUNK][64];     // 2 bufs x 4 waves x 5 t x 64 lanes = 20 KB

    const int tid  = threadIdx.x;
    const int lane = tid & 63;
    const int wq   = __builtin_amdgcn_readfirstlane(tid >> 6);  // neuron quarter
    const int b0   = blockIdx.x * 64;

    // cooperative coalesced x stage (64 rows x 9 f32)
    for (int i = tid; i < 64 * NIN; i += 256) sx[i] = x[(size_t)b0 * NIN + i];
    __syncthreads();

    // per-lane x row widened to f64 (18 VGPRs)
    double xv[NIN];
#pragma unroll
    for (int i = 0; i < NIN; ++i) xv[i] = (double)sx[lane * NIN + i];

    // per-step fc2 partial sums: packed f32 (50 VGPRs, arch file)
    v2f acc[TSTEPS];
#pragma unroll
    for (int t = 0; t < TSTEPS; ++t) acc[t] = (v2f){0.f, 0.f};

    const int h0 = wq * 25;
#pragma unroll 1
    for (int j = 0; j < 25; ++j) {
        const int h = h0 + j;                  // wave-uniform
        double c = 0.0;
#pragma unroll
        for (int i = 0; i < NIN; ++i)
            c += (double)W1[h * NIN + i] * xv[i];   // s_load + cvt, fma
        c += (double)b1[h];
        double c1 = c - 1.0;                   // addend when previous step spiked
        v2f w = (v2f){W2[h], W2[NHID + h]};    // uniform -> sgpr, broadcast to vgpr

        double m = 0.0;
        bool s = false;                        // spike(t-1) == reset(t)
#pragma unroll
        for (int t = 0; t < TSTEPS; ++t) {
            m = 0.95 * m + (s ? c1 : c);       // f64 leaky integrate + fused reset
            s = (m > 1.0);                     // f64 spike decision
            float d = s ? 1.f : 0.f;
            acc[t] += (v2f){d, d} * w;         // ascending-j order preserved
        }
    }

    // chunked cross-wave reduce + mem2 (wave 0), double-buffered LDS
    double m20 = 0.0, m21 = 0.0;
    double bb0 = (double)b2[0], bb1 = (double)b2[1];

#pragma unroll 1
    for (int k = 0; k < TSTEPS / CHUNK; ++k) {
#pragma unroll
        for (int u = 0; u < CHUNK; ++u)
            sacc[k & 1][wq][u][lane] = acc[k * CHUNK + u];
        __syncthreads();
        // wave0 reads buf[k&1] before it reaches the NEXT barrier; other waves
        // can't overwrite buf[k&1] until chunk k+2's writes, which sit behind
        // that barrier -> safe with a single sync per chunk.
        if (wq == 0) {
#pragma unroll
            for (int u = 0; u < CHUNK; ++u) {
                const int t = k * CHUNK + u;
                v2f a0 = sacc[k & 1][0][u][lane];
                v2f a1 = sacc[k & 1][1][u][lane];
                v2f a2 = sacc[k & 1][2][u][lane];
                v2f a3 = sacc[k & 1][3][u][lane];
                v2f sum = (a0 + a1) + (a2 + a3);   // butterfly bracketing
                double r0 = (m20 > 1.0) ? 1.0 : 0.0;
                double r1 = (m21 > 1.0) ? 1.0 : 0.0;
                m20 = 0.95 * m20 + ((double)sum[0] + bb0) - r0;
                m21 = 0.95 * m21 + ((double)sum[1] + bb1) - r1;
                *(float2*)(out + ((size_t)t * BATCH + b0 + lane) * 2) =
                    make_float2((float)m20, (float)m21);
            }
        }
    }
}

extern "C" void kernel_launch(void* const* d_in, const int* in_sizes, int n_in,
                              void* d_out, int out_size, void* d_ws, size_t ws_size,
                              hipStream_t stream) {
    const float* x  = (const float*)d_in[0];
    const float* W1 = (const float*)d_in[1];
    const float* b1 = (const float*)d_in[2];
    const float* W2 = (const float*)d_in[3];
    const float* b2 = (const float*)d_in[4];
    float* out = (float*)d_out;

    dim3 grid(BATCH / 64), block(256);
    hipLaunchKernelGGL(snn_kernel, grid, block, 0, stream, x, W1, b1, W2, b2, out);
}

// Round 10
// 100.387 us; speedup vs baseline: 1.0924x; 1.0924x over previous
//
#include <hip/hip_runtime.h>

#define BATCH  65536
#define NIN    9
#define NHID   100
#define TSTEPS 25
#define CHUNK  5

typedef float v2f __attribute__((ext_vector_type(2)));

// Wave-uniform neuron mapping: block = 64 batch elements (lane = batch elem),
// wave wq owns neuron rows [25wq, 25wq+25) -> weight reads are wave-uniform
// => scalar (SGPR) loads, zero VALU issue for weights/addressing.
// f64 m-chain per neuron-step (tracks the f64 numpy arbiter), packed f32 fc2
// acc in arch VGPRs. ROUND-10 FIX: the epilogue chunk loop is FULLY UNROLLED —
// round 9's `#pragma unroll 1` made acc[k*CHUNK+u] dynamically indexed and
// spilled the whole acc[25] array to scratch (WRITE_SIZE 83.5 MB, VGPR=40).
// Every acc index must be a compile-time constant.
__global__ __launch_bounds__(256) void snn_kernel(
    const float* __restrict__ x,  const float* __restrict__ W1,
    const float* __restrict__ b1, const float* __restrict__ W2,
    const float* __restrict__ b2, float* __restrict__ out)
{
    __shared__ float sx[64 * NIN];              // 2.25 KB staged x rows
    __shared__ v2f   sacc[2][4][CHUNK][64];     // 2 bufs x 4 waves x 5 t x 64 lanes = 20 KB

    const int tid  = threadIdx.x;
    const int lane = tid & 63;
    const int wq   = __builtin_amdgcn_readfirstlane(tid >> 6);  // neuron quarter
    const int b0   = blockIdx.x * 64;

    // cooperative coalesced x stage (64 rows x 9 f32)
    for (int i = tid; i < 64 * NIN; i += 256) sx[i] = x[(size_t)b0 * NIN + i];
    __syncthreads();

    // per-lane x row widened to f64 (18 VGPRs)
    double xv[NIN];
#pragma unroll
    for (int i = 0; i < NIN; ++i) xv[i] = (double)sx[lane * NIN + i];

    // per-step fc2 partial sums: packed f32 (50 VGPRs, arch file)
    v2f acc[TSTEPS];
#pragma unroll
    for (int t = 0; t < TSTEPS; ++t) acc[t] = (v2f){0.f, 0.f};

    const int h0 = wq * 25;
#pragma unroll 1
    for (int j = 0; j < 25; ++j) {
        const int h = h0 + j;                  // wave-uniform
        double c = 0.0;
#pragma unroll
        for (int i = 0; i < NIN; ++i)
            c += (double)W1[h * NIN + i] * xv[i];   // s_load + cvt, fma
        c += (double)b1[h];
        double c1 = c - 1.0;                   // addend when previous step spiked
        v2f w = (v2f){W2[h], W2[NHID + h]};    // uniform -> sgpr, broadcast

        double m = 0.0;
        bool s = false;                        // spike(t-1) == reset(t)
#pragma unroll
        for (int t = 0; t < TSTEPS; ++t) {
            m = 0.95 * m + (s ? c1 : c);       // f64 leaky integrate + fused reset
            s = (m > 1.0);                     // f64 spike decision
            float d = s ? 1.f : 0.f;
            acc[t] += (v2f){d, d} * w;         // ascending-j order preserved
        }
    }

    // chunked cross-wave reduce + mem2 (wave 0), double-buffered LDS.
    // FULLY UNROLLED: all acc[] indices compile-time constants.
    double m20 = 0.0, m21 = 0.0;
    double bb0 = (double)b2[0], bb1 = (double)b2[1];

#pragma unroll
    for (int k = 0; k < TSTEPS / CHUNK; ++k) {
#pragma unroll
        for (int u = 0; u < CHUNK; ++u)
            sacc[k & 1][wq][u][lane] = acc[k * CHUNK + u];
        __syncthreads();
        // wave0 reads buf[k&1] before the NEXT barrier; other waves can't
        // overwrite buf[k&1] until chunk k+2's writes, which sit behind that
        // barrier -> safe with one sync per chunk.
        if (wq == 0) {
#pragma unroll
            for (int u = 0; u < CHUNK; ++u) {
                const int t = k * CHUNK + u;
                v2f a0 = sacc[k & 1][0][u][lane];
                v2f a1 = sacc[k & 1][1][u][lane];
                v2f a2 = sacc[k & 1][2][u][lane];
                v2f a3 = sacc[k & 1][3][u][lane];
                v2f sum = (a0 + a1) + (a2 + a3);   // butterfly bracketing
                double r0 = (m20 > 1.0) ? 1.0 : 0.0;
                double r1 = (m21 > 1.0) ? 1.0 : 0.0;
                m20 = 0.95 * m20 + ((double)sum[0] + bb0) - r0;
                m21 = 0.95 * m21 + ((double)sum[1] + bb1) - r1;
                *(float2*)(out + ((size_t)t * BATCH + b0 + lane) * 2) =
                    make_float2((float)m20, (float)m21);
            }
        }
    }
}

extern "C" void kernel_launch(void* const* d_in, const int* in_sizes, int n_in,
                              void* d_out, int out_size, void* d_ws, size_t ws_size,
                              hipStream_t stream) {
    const float* x  = (const float*)d_in[0];
    const float* W1 = (const float*)d_in[1];
    const float* b1 = (const float*)d_in[2];
    const float* W2 = (const float*)d_in[3];
    const float* b2 = (const float*)d_in[4];
    float* out = (float*)d_out;

    dim3 grid(BATCH / 64), block(256);
    hipLaunchKernelGGL(snn_kernel, grid, block, 0, stream, x, W1, b1, W2, b2, out);
}

// Round 11
// 100.309 us; speedup vs baseline: 1.0932x; 1.0008x over previous
//
#include <hip/hip_runtime.h>

#define BATCH  65536
#define NIN    9
#define NHID   100
#define TSTEPS 25
#define CHUNK  5

typedef float v2f __attribute__((ext_vector_type(2)));

// Wave-uniform neuron mapping: block = 64 batch elements (lane = batch elem),
// wave wq owns neuron rows [25wq, 25wq+25) -> weight reads are wave-uniform
// scalar (SGPR) loads. f64 m-chain (tracks the f64 numpy arbiter), packed f32
// fc2 acc. ROUND-11: __launch_bounds__(256,1) gives the allocator a 512-reg
// budget so acc[25] lands in ARCH VGPRs instead of AGPRs — rounds 5-10 all
// show VGPR_Count<=60 (impossible with 50-reg acc live) plus ~6 cyc/step of
// unexplained issue == v_accvgpr read/write brackets around every acc FMA.
// j-loop unrolled x5 so wave-uniform s_loads batch and their SMEM latency is
// covered by the previous neurons' t-loops.
__global__ __launch_bounds__(256, 1) void snn_kernel(
    const float* __restrict__ x,  const float* __restrict__ W1,
    const float* __restrict__ b1, const float* __restrict__ W2,
    const float* __restrict__ b2, float* __restrict__ out)
{
    __shared__ float sx[64 * NIN];              // 2.25 KB staged x rows
    __shared__ v2f   sacc[2][4][CHUNK][64];     // 2 bufs x 4 waves x 5 t x 64 lanes = 20 KB

    const int tid  = threadIdx.x;
    const int lane = tid & 63;
    const int wq   = __builtin_amdgcn_readfirstlane(tid >> 6);  // neuron quarter
    const int b0   = blockIdx.x * 64;

    // cooperative coalesced x stage (64 rows x 9 f32)
    for (int i = tid; i < 64 * NIN; i += 256) sx[i] = x[(size_t)b0 * NIN + i];
    __syncthreads();

    // per-lane x row widened to f64 (18 VGPRs — budget is loose now)
    double xv[NIN];
#pragma unroll
    for (int i = 0; i < NIN; ++i) xv[i] = (double)sx[lane * NIN + i];

    // per-step fc2 partial sums: packed f32 (50 VGPRs, arch file)
    v2f acc[TSTEPS];
#pragma unroll
    for (int t = 0; t < TSTEPS; ++t) acc[t] = (v2f){0.f, 0.f};

    const int h0 = wq * 25;
#pragma unroll 5
    for (int j = 0; j < 25; ++j) {
        const int h = h0 + j;                  // wave-uniform
        double c = 0.0;
#pragma unroll
        for (int i = 0; i < NIN; ++i)
            c += (double)W1[h * NIN + i] * xv[i];   // s_load + cvt, fma
        c += (double)b1[h];
        double c1 = c - 1.0;                   // addend when previous step spiked
        v2f w = (v2f){W2[h], W2[NHID + h]};    // uniform -> sgpr, broadcast

        double m = 0.0;
        bool s = false;                        // spike(t-1) == reset(t)
#pragma unroll
        for (int t = 0; t < TSTEPS; ++t) {
            m = 0.95 * m + (s ? c1 : c);       // f64 leaky integrate + fused reset
            s = (m > 1.0);                     // f64 spike decision
            float d = s ? 1.f : 0.f;
            acc[t] += (v2f){d, d} * w;         // ascending-j order preserved
        }
    }

    // chunked cross-wave reduce + mem2 (wave 0), double-buffered LDS.
    // Fully unrolled: all acc[] indices compile-time constants (round-9 bug).
    double m20 = 0.0, m21 = 0.0;
    double bb0 = (double)b2[0], bb1 = (double)b2[1];

#pragma unroll
    for (int k = 0; k < TSTEPS / CHUNK; ++k) {
#pragma unroll
        for (int u = 0; u < CHUNK; ++u)
            sacc[k & 1][wq][u][lane] = acc[k * CHUNK + u];
        __syncthreads();
        // wave0 reads buf[k&1] before the NEXT barrier; other waves can't
        // overwrite buf[k&1] until chunk k+2's writes, behind that barrier.
        if (wq == 0) {
#pragma unroll
            for (int u = 0; u < CHUNK; ++u) {
                const int t = k * CHUNK + u;
                v2f a0 = sacc[k & 1][0][u][lane];
                v2f a1 = sacc[k & 1][1][u][lane];
                v2f a2 = sacc[k & 1][2][u][lane];
                v2f a3 = sacc[k & 1][3][u][lane];
                v2f sum = (a0 + a1) + (a2 + a3);   // butterfly bracketing
                double r0 = (m20 > 1.0) ? 1.0 : 0.0;
                double r1 = (m21 > 1.0) ? 1.0 : 0.0;
                m20 = 0.95 * m20 + ((double)sum[0] + bb0) - r0;
                m21 = 0.95 * m21 + ((double)sum[1] + bb1) - r1;
                *(float2*)(out + ((size_t)t * BATCH + b0 + lane) * 2) =
                    make_float2((float)m20, (float)m21);
            }
        }
    }
}

extern "C" void kernel_launch(void* const* d_in, const int* in_sizes, int n_in,
                              void* d_out, int out_size, void* d_ws, size_t ws_size,
                              hipStream_t stream) {
    const float* x  = (const float*)d_in[0];
    const float* W1 = (const float*)d_in[1];
    const float* b1 = (const float*)d_in[2];
    const float* W2 = (const float*)d_in[3];
    const float* b2 = (const float*)d_in[4];
    float* out = (float*)d_out;

    dim3 grid(BATCH / 64), block(256);
    hipLaunchKernelGGL(snn_kernel, grid, block, 0, stream, x, W1, b1, W2, b2, out);
}

// Round 12
// 99.225 us; speedup vs baseline: 1.1051x; 1.0109x over previous
//
#include <hip/hip_runtime.h>

#define BATCH  65536
#define NIN    9
#define NHID   100
#define TSTEPS 25
#define CHUNK  5

typedef float v2f __attribute__((ext_vector_type(2)));

// Wave-uniform neuron mapping (block = 64 batch elems, wave wq owns neurons
// [25wq,25wq+25)): weights via SGPR scalar loads. f64 m-chain (tracks the f64
// numpy arbiter). ROUND-12: the per-step fc2 accumulators are updated through
// inline-asm v_fmac_f32 with "+v" tied operands — a register-CLASS constraint
// the allocator cannot ignore. Rounds 5-11 show VGPR_Count<=60 with 50+ floats
// of acc live => acc lives in AGPRs with v_accvgpr read/write brackets
// (~8 cyc/neuron-step tax, the gap between measured 26 cyc/step and the
// 18-cyc instruction model). v_fmac_f32 == fmaf -> bit-identical output.
__global__ __launch_bounds__(256) void snn_kernel(
    const float* __restrict__ x,  const float* __restrict__ W1,
    const float* __restrict__ b1, const float* __restrict__ W2,
    const float* __restrict__ b2, float* __restrict__ out)
{
    __shared__ float sx[64 * NIN];              // 2.25 KB staged x rows
    __shared__ v2f   sacc[2][4][CHUNK][64];     // 20 KB, double-buffered reduce

    const int tid  = threadIdx.x;
    const int lane = tid & 63;
    const int wq   = __builtin_amdgcn_readfirstlane(tid >> 6);  // neuron quarter
    const int b0   = blockIdx.x * 64;

    // cooperative coalesced x stage (64 rows x 9 f32)
    for (int i = tid; i < 64 * NIN; i += 256) sx[i] = x[(size_t)b0 * NIN + i];
    __syncthreads();

    // per-lane x row widened to f64
    double xv[NIN];
#pragma unroll
    for (int i = 0; i < NIN; ++i) xv[i] = (double)sx[lane * NIN + i];

    // per-step fc2 partial sums — pinned to arch VGPRs via asm "+v" uses
    float a0[TSTEPS], a1[TSTEPS];
#pragma unroll
    for (int t = 0; t < TSTEPS; ++t) { a0[t] = 0.f; a1[t] = 0.f; }

    const int h0 = wq * 25;
#pragma unroll 1
    for (int j = 0; j < 25; ++j) {
        const int h = h0 + j;                  // wave-uniform
        double c = 0.0;
#pragma unroll
        for (int i = 0; i < NIN; ++i)
            c += (double)W1[h * NIN + i] * xv[i];   // s_load + cvt, fma_f64
        c += (double)b1[h];
        double c1 = c - 1.0;                   // addend when previous step spiked
        float w0 = W2[h], w1 = W2[NHID + h];   // uniform scalar loads

        double m = 0.0;
        bool s = false;                        // spike(t-1) == reset(t)
#pragma unroll
        for (int t = 0; t < TSTEPS; ++t) {
            m = 0.95 * m + (s ? c1 : c);       // f64 leaky integrate + fused reset
            s = (m > 1.0);                     // f64 spike decision
            float d = s ? 1.f : 0.f;
            // v_fmac_f32 == fmaf(d,w,acc): bit-identical to prior rounds,
            // but the "+v" tie forces a0/a1 into arch VGPRs (no accvgpr moves)
            asm("v_fmac_f32 %0, %1, %2" : "+v"(a0[t]) : "v"(d), "v"(w0));
            asm("v_fmac_f32 %0, %1, %2" : "+v"(a1[t]) : "v"(d), "v"(w1));
        }
    }

    // chunked cross-wave reduce + mem2 (wave 0), double-buffered LDS.
    // Fully unrolled: all acc indices compile-time constants (round-9 lesson).
    double m20 = 0.0, m21 = 0.0;
    double bb0 = (double)b2[0], bb1 = (double)b2[1];

#pragma unroll
    for (int k = 0; k < TSTEPS / CHUNK; ++k) {
#pragma unroll
        for (int u = 0; u < CHUNK; ++u)
            sacc[k & 1][wq][u][lane] = (v2f){a0[k * CHUNK + u], a1[k * CHUNK + u]};
        __syncthreads();
        // wave0 reads buf[k&1] before the NEXT barrier; other waves can't
        // overwrite buf[k&1] until chunk k+2's writes, behind that barrier.
        if (wq == 0) {
#pragma unroll
            for (int u = 0; u < CHUNK; ++u) {
                const int t = k * CHUNK + u;
                v2f q0 = sacc[k & 1][0][u][lane];
                v2f q1 = sacc[k & 1][1][u][lane];
                v2f q2 = sacc[k & 1][2][u][lane];
                v2f q3 = sacc[k & 1][3][u][lane];
                v2f sum = (q0 + q1) + (q2 + q3);   // butterfly bracketing
                double r0 = (m20 > 1.0) ? 1.0 : 0.0;
                double r1 = (m21 > 1.0) ? 1.0 : 0.0;
                m20 = 0.95 * m20 + ((double)sum[0] + bb0) - r0;
                m21 = 0.95 * m21 + ((double)sum[1] + bb1) - r1;
                *(float2*)(out + ((size_t)t * BATCH + b0 + lane) * 2) =
                    make_float2((float)m20, (float)m21);
            }
        }
    }
}

extern "C" void kernel_launch(void* const* d_in, const int* in_sizes, int n_in,
                              void* d_out, int out_size, void* d_ws, size_t ws_size,
                              hipStream_t stream) {
    const float* x  = (const float*)d_in[0];
    const float* W1 = (const float*)d_in[1];
    const float* b1 = (const float*)d_in[2];
    const float* W2 = (const float*)d_in[3];
    const float* b2 = (const float*)d_in[4];
    float* out = (float*)d_out;

    dim3 grid(BATCH / 64), block(256);
    hipLaunchKernelGGL(snn_kernel, grid, block, 0, stream, x, W1, b1, W2, b2, out);
}